// Round 1
// baseline (1998.343 us; speedup 1.0000x reference)
//
#include <hip/hip_runtime.h>
#include <math.h>

static constexpr int BROWS = 16384;
static constexpr int IND   = 128;
static constexpr int DE    = 512;   // DENC
static constexpr int DOUTD = 256;   // dim_encoder_out
static constexpr int ED    = 64;    // codebook dim
static constexpr int NE    = 1024;  // codebook entries

// d_out layout (floats): [0]=loss, [1..2097152]=x_hat(16384x128), [2097153]=perplexity,
// [2097154..6291457]=z_q_st(16384x256), [6291458..6356993]=idx(65536)
static constexpr size_t O_XHAT = 1;
static constexpr size_t O_PERP = 2097153;
static constexpr size_t O_ZQ   = 2097154;
static constexpr size_t O_IDX  = 6291458;

__device__ inline float wave_sum(float v) {
#pragma unroll
    for (int o = 32; o >= 1; o >>= 1) v += __shfl_xor(v, o, 64);
    return v;
}

// ---------------- GEMM: C[M][N] = A[M][K] @ W[N][K]^T + bias ; EPI==1: scale*v+shift ----
template<int K, int EPI>
__global__ __launch_bounds__(256)
void gemm_k(const float* __restrict__ A, const float* __restrict__ W,
            const float* __restrict__ bias, float* __restrict__ C, int N,
            const float* __restrict__ escale, const float* __restrict__ eshift)
{
    __shared__ float As[32][68];
    __shared__ float Ws[32][68];
    const int tid = threadIdx.x;
    const int bm = blockIdx.y << 6;
    const int bn = blockIdx.x << 6;
    const int tx = tid & 15, ty = tid >> 4;
    float acc[4][4] = {};
    for (int k0 = 0; k0 < K; k0 += 32) {
#pragma unroll
        for (int q0 = 0; q0 < 512; q0 += 256) {
            int q = q0 + tid;
            int r = q >> 3, c4 = (q & 7) << 2;
            float4 va = *(const float4*)(A + (size_t)(bm + r) * K + (k0 + c4));
            As[c4 + 0][r] = va.x; As[c4 + 1][r] = va.y; As[c4 + 2][r] = va.z; As[c4 + 3][r] = va.w;
            float4 vw = *(const float4*)(W + (size_t)(bn + r) * K + (k0 + c4));
            Ws[c4 + 0][r] = vw.x; Ws[c4 + 1][r] = vw.y; Ws[c4 + 2][r] = vw.z; Ws[c4 + 3][r] = vw.w;
        }
        __syncthreads();
#pragma unroll
        for (int kk = 0; kk < 32; ++kk) {
            float4 a4 = *(const float4*)(&As[kk][ty << 2]);
            float4 b4 = *(const float4*)(&Ws[kk][tx << 2]);
            float av_[4] = {a4.x, a4.y, a4.z, a4.w};
            float bv_[4] = {b4.x, b4.y, b4.z, b4.w};
#pragma unroll
            for (int i = 0; i < 4; ++i)
#pragma unroll
                for (int j = 0; j < 4; ++j)
                    acc[i][j] = fmaf(av_[i], bv_[j], acc[i][j]);
        }
        __syncthreads();
    }
#pragma unroll
    for (int i = 0; i < 4; ++i) {
        int m = bm + (ty << 2) + i;
#pragma unroll
        for (int j = 0; j < 4; ++j) {
            int n = bn + (tx << 2) + j;
            float v = acc[i][j] + bias[n];
            if (EPI == 1) v = escale[n] * v + eshift[n];
            C[(size_t)m * N + n] = v;
        }
    }
}

// -------------- input normalization: xs = (x - shift) / scale ---------------------------
__global__ __launch_bounds__(256)
void prep_k(const float* __restrict__ x, const float* __restrict__ scale,
            const float* __restrict__ shift, float* __restrict__ xs)
{
    int g = blockIdx.x * 256 + threadIdx.x;
    int col = g & (IND - 1);
    xs[g] = (x[g] - shift[col]) / scale[col];
}

// -------------- fused encoder resblock tail: av=av+relu(ln(tav)); h=(h+relu(ln(th)))*av -
__global__ __launch_bounds__(256)
void ln_enc_k(const float* __restrict__ tav, const float* __restrict__ th,
              float* __restrict__ av, float* __restrict__ h,
              const float* __restrict__ ag, const float* __restrict__ abe,
              const float* __restrict__ wg, const float* __restrict__ wbe)
{
    const int lane = threadIdx.x & 63;
    const int row  = (blockIdx.x << 2) + (threadIdx.x >> 6);
    const int col  = lane << 3;
    const size_t base = (size_t)row * DE + col;

    float t[8];
    { float4 p0 = *(const float4*)(tav + base); float4 p1 = *(const float4*)(tav + base + 4);
      t[0]=p0.x; t[1]=p0.y; t[2]=p0.z; t[3]=p0.w; t[4]=p1.x; t[5]=p1.y; t[6]=p1.z; t[7]=p1.w; }
    float s = 0.f;
#pragma unroll
    for (int i = 0; i < 8; ++i) s += t[i];
    s = wave_sum(s);
    float mean = s * (1.0f / 512.0f);
    float vs = 0.f;
#pragma unroll
    for (int i = 0; i < 8; ++i) { float d = t[i] - mean; vs += d * d; }
    vs = wave_sum(vs);
    float rstd = 1.0f / sqrtf(vs * (1.0f / 512.0f) + 1e-5f);

    float avn[8];
    { float4 p0 = *(const float4*)(av + base); float4 p1 = *(const float4*)(av + base + 4);
      float avv[8] = {p0.x,p0.y,p0.z,p0.w,p1.x,p1.y,p1.z,p1.w};
#pragma unroll
      for (int i = 0; i < 8; ++i) {
          float lnv = (t[i] - mean) * rstd * ag[col + i] + abe[col + i];
          avn[i] = avv[i] + fmaxf(lnv, 0.0f);
      }
      float4 o0 = {avn[0],avn[1],avn[2],avn[3]}, o1 = {avn[4],avn[5],avn[6],avn[7]};
      *(float4*)(av + base) = o0; *(float4*)(av + base + 4) = o1; }

    // h path
    { float4 p0 = *(const float4*)(th + base); float4 p1 = *(const float4*)(th + base + 4);
      t[0]=p0.x; t[1]=p0.y; t[2]=p0.z; t[3]=p0.w; t[4]=p1.x; t[5]=p1.y; t[6]=p1.z; t[7]=p1.w; }
    s = 0.f;
#pragma unroll
    for (int i = 0; i < 8; ++i) s += t[i];
    s = wave_sum(s);
    float mean2 = s * (1.0f / 512.0f);
    vs = 0.f;
#pragma unroll
    for (int i = 0; i < 8; ++i) { float d = t[i] - mean2; vs += d * d; }
    vs = wave_sum(vs);
    float rstd2 = 1.0f / sqrtf(vs * (1.0f / 512.0f) + 1e-5f);
    { float4 p0 = *(const float4*)(h + base); float4 p1 = *(const float4*)(h + base + 4);
      float hv[8] = {p0.x,p0.y,p0.z,p0.w,p1.x,p1.y,p1.z,p1.w};
      float hn[8];
#pragma unroll
      for (int i = 0; i < 8; ++i) {
          float lnv = (t[i] - mean2) * rstd2 * wg[col + i] + wbe[col + i];
          hn[i] = (hv[i] + fmaxf(lnv, 0.0f)) * avn[i];
      }
      float4 o0 = {hn[0],hn[1],hn[2],hn[3]}, o1 = {hn[4],hn[5],hn[6],hn[7]};
      *(float4*)(h + base) = o0; *(float4*)(h + base + 4) = o1; }
}

// -------------- decoder resblock tail: h = h + relu(ln(t)) ------------------------------
__global__ __launch_bounds__(256)
void ln_dec_k(const float* __restrict__ t_, float* __restrict__ h,
              const float* __restrict__ g, const float* __restrict__ be)
{
    const int lane = threadIdx.x & 63;
    const int row  = (blockIdx.x << 2) + (threadIdx.x >> 6);
    const int col  = lane << 3;
    const size_t base = (size_t)row * DE + col;
    float t[8];
    { float4 p0 = *(const float4*)(t_ + base); float4 p1 = *(const float4*)(t_ + base + 4);
      t[0]=p0.x; t[1]=p0.y; t[2]=p0.z; t[3]=p0.w; t[4]=p1.x; t[5]=p1.y; t[6]=p1.z; t[7]=p1.w; }
    float s = 0.f;
#pragma unroll
    for (int i = 0; i < 8; ++i) s += t[i];
    s = wave_sum(s);
    float mean = s * (1.0f / 512.0f);
    float vs = 0.f;
#pragma unroll
    for (int i = 0; i < 8; ++i) { float d = t[i] - mean; vs += d * d; }
    vs = wave_sum(vs);
    float rstd = 1.0f / sqrtf(vs * (1.0f / 512.0f) + 1e-5f);
    { float4 p0 = *(const float4*)(h + base); float4 p1 = *(const float4*)(h + base + 4);
      float hv[8] = {p0.x,p0.y,p0.z,p0.w,p1.x,p1.y,p1.z,p1.w};
      float hn[8];
#pragma unroll
      for (int i = 0; i < 8; ++i) {
          float lnv = (t[i] - mean) * rstd * g[col + i] + be[col + i];
          hn[i] = hv[i] + fmaxf(lnv, 0.0f);
      }
      float4 o0 = {hn[0],hn[1],hn[2],hn[3]}, o1 = {hn[4],hn[5],hn[6],hn[7]};
      *(float4*)(h + base) = o0; *(float4*)(h + base + 4) = o1; }
}

// -------------- codebook squared norms --------------------------------------------------
__global__ __launch_bounds__(256)
void c2_k(const float* __restrict__ cb, float* __restrict__ c2)
{
    int j = blockIdx.x * 256 + threadIdx.x;
    if (j < NE) {
        float s = 0.f;
        const float* p = cb + (size_t)j * ED;
#pragma unroll
        for (int d = 0; d < ED; ++d) s = fmaf(p[d], p[d], s);
        c2[j] = s;
    }
}

// -------------- VQ: argmin over 1024 codes, gather z_q, loss partials, counts -----------
__global__ __launch_bounds__(256)
void vq_k(const float* __restrict__ ze, const float* __restrict__ cb, const float* __restrict__ c2,
          float* __restrict__ zq_ws, float* __restrict__ idx_out,
          int* __restrict__ counts, float* __restrict__ partials)
{
    __shared__ float cbs[128 * 64];   // 32 KB codebook tile
    __shared__ float c2s[128];
    __shared__ float red[4];
    const int tid = threadIdx.x;
    const size_t i = (size_t)blockIdx.x * 256 + tid;

    float z[64];
#pragma unroll
    for (int d = 0; d < 64; d += 4) {
        float4 v = *(const float4*)(ze + i * 64 + d);
        z[d] = v.x; z[d + 1] = v.y; z[d + 2] = v.z; z[d + 3] = v.w;
    }
    float z2 = 0.f;
#pragma unroll
    for (int d = 0; d < 64; ++d) z2 = fmaf(z[d], z[d], z2);

    float best = INFINITY; int bi = 0;
    for (int t0 = 0; t0 < NE; t0 += 128) {
        __syncthreads();
#pragma unroll
        for (int q0 = 0; q0 < 2048; q0 += 256)
            ((float4*)cbs)[q0 + tid] = ((const float4*)(cb + (size_t)t0 * 64))[q0 + tid];
        if (tid < 128) c2s[tid] = c2[t0 + tid];
        __syncthreads();
        for (int j = 0; j < 128; ++j) {
            const float* cj = &cbs[j * 64];
            float dot = 0.f;
#pragma unroll
            for (int d = 0; d < 64; d += 4) {
                float4 c4 = *(const float4*)(cj + d);
                dot = fmaf(z[d], c4.x, dot);
                dot = fmaf(z[d + 1], c4.y, dot);
                dot = fmaf(z[d + 2], c4.z, dot);
                dot = fmaf(z[d + 3], c4.w, dot);
            }
            // mimic numpy: d = (z2 + c2) - 2*dot, with explicit rounding, no fma-contraction
            float term = __fadd_rn(z2, c2s[j]);
            float dist = __fsub_rn(term, __fmul_rn(2.0f, dot));
            if (dist < best) { best = dist; bi = t0 + j; }
        }
    }
    idx_out[i] = (float)bi;
    float lsum = 0.f;
    const float* cq = cb + (size_t)bi * 64;
#pragma unroll
    for (int d = 0; d < 64; d += 4) {
        float4 q4 = *(const float4*)(cq + d);
        *(float4*)(zq_ws + i * 64 + d) = q4;
        float d0 = q4.x - z[d], d1 = q4.y - z[d + 1], d2 = q4.z - z[d + 2], d3 = q4.w - z[d + 3];
        lsum = fmaf(d0, d0, lsum); lsum = fmaf(d1, d1, lsum);
        lsum = fmaf(d2, d2, lsum); lsum = fmaf(d3, d3, lsum);
    }
    atomicAdd(&counts[bi], 1);
    lsum = wave_sum(lsum);
    if ((tid & 63) == 0) red[tid >> 6] = lsum;
    __syncthreads();
    if (tid == 0) partials[blockIdx.x] = ((red[0] + red[1]) + red[2]) + red[3];
}

// -------------- copy (handles unaligned d_out offsets with scalar dwords) ---------------
__global__ __launch_bounds__(256)
void copy_k(const float* __restrict__ src, float* __restrict__ dst, int n)
{
    int g = blockIdx.x * 256 + threadIdx.x;
    if (g < n) dst[g] = src[g];
}

// -------------- finalize: loss + perplexity ---------------------------------------------
__global__ __launch_bounds__(256)
void fin_k(const float* __restrict__ partials, const int* __restrict__ counts,
           float* __restrict__ loss_out, float* __restrict__ perp_out)
{
    __shared__ float red[4];
    __shared__ float red2[4];
    const int tid = threadIdx.x;
    float v = partials[tid];
    float s = wave_sum(v);
    if ((tid & 63) == 0) red[tid >> 6] = s;
    float ep = 0.f;
    for (int c = tid; c < NE; c += 256) {
        float e = (float)counts[c] * (1.0f / 65536.0f);
        ep += e * logf(e + 1e-10f);
    }
    ep = wave_sum(ep);
    if ((tid & 63) == 0) red2[tid >> 6] = ep;
    __syncthreads();
    if (tid == 0) {
        float S = ((red[0] + red[1]) + red[2]) + red[3];
        float E = ((red2[0] + red2[1]) + red2[2]) + red2[3];
        loss_out[0] = 1.25f * (S * (1.0f / 4194304.0f));  // (1+BETA) * mean
        perp_out[0] = expf(-E);
    }
}

extern "C" void kernel_launch(void* const* d_in, const int* in_sizes, int n_in,
                              void* d_out, int out_size, void* d_ws, size_t ws_size,
                              hipStream_t stream)
{
    const float* x       = (const float*)d_in[0];
    const float* a       = (const float*)d_in[1];
    const float* scale   = (const float*)d_in[2];
    const float* shift   = (const float*)d_in[3];
    const float* win_w   = (const float*)d_in[4];
    const float* win_b   = (const float*)d_in[5];
    const float* ain_w   = (const float*)d_in[6];
    const float* ain_b   = (const float*)d_in[7];
    const float* wres_w  = (const float*)d_in[8];
    const float* wres_b  = (const float*)d_in[9];
    const float* wres_g  = (const float*)d_in[10];
    const float* wres_be = (const float*)d_in[11];
    const float* ares_w  = (const float*)d_in[12];
    const float* ares_b  = (const float*)d_in[13];
    const float* ares_g  = (const float*)d_in[14];
    const float* ares_be = (const float*)d_in[15];
    const float* out_w   = (const float*)d_in[16];
    const float* out_b   = (const float*)d_in[17];
    const float* dec1_w  = (const float*)d_in[18];
    const float* dec1_b  = (const float*)d_in[19];
    const float* dres_w  = (const float*)d_in[20];
    const float* dres_b  = (const float*)d_in[21];
    const float* dres_g  = (const float*)d_in[22];
    const float* dres_be = (const float*)d_in[23];
    const float* dec2_w  = (const float*)d_in[24];
    const float* dec2_b  = (const float*)d_in[25];
    const float* cb      = (const float*)d_in[26];

    float* ws = (float*)d_ws;
    const size_t SZ_BD = (size_t)BROWS * DE;      // 8388608
    float* A1 = ws;                // av  -> later hd (decoder)
    float* A2 = A1 + SZ_BD;        // h   -> later t (decoder)
    float* A3 = A2 + SZ_BD;        // xs  -> t_av -> z_q (aligned copy)
    float* A4 = A3 + SZ_BD;        // t_h
    float* A5 = A4 + SZ_BD;        // z_e (BROWS x 256)
    float* SMALL = A5 + (size_t)BROWS * DOUTD;
    float* c2v      = SMALL;                 // 1024
    int*   counts   = (int*)(SMALL + 1024);  // 1024
    float* partials = SMALL + 2048;          // 256

    float* dout = (float*)d_out;

    // --- input normalization ---
    prep_k<<<(BROWS * IND) / 256, 256, 0, stream>>>(x, scale, shift, A3);
    // --- input projections ---
    gemm_k<128, 0><<<dim3(DE / 64, BROWS / 64), 256, 0, stream>>>(a,  ain_w, ain_b, A1, DE, nullptr, nullptr);
    gemm_k<128, 0><<<dim3(DE / 64, BROWS / 64), 256, 0, stream>>>(A3, win_w, win_b, A2, DE, nullptr, nullptr);
    // --- encoder resblocks (shared weights, interleaved av-mul) ---
    for (int r = 0; r < 3; ++r) {
        gemm_k<512, 0><<<dim3(DE / 64, BROWS / 64), 256, 0, stream>>>(A1, ares_w, ares_b, A3, DE, nullptr, nullptr);
        gemm_k<512, 0><<<dim3(DE / 64, BROWS / 64), 256, 0, stream>>>(A2, wres_w, wres_b, A4, DE, nullptr, nullptr);
        ln_enc_k<<<BROWS / 4, 256, 0, stream>>>(A3, A4, A1, A2, ares_g, ares_be, wres_g, wres_be);
    }
    // --- z_e ---
    gemm_k<512, 0><<<dim3(DOUTD / 64, BROWS / 64), 256, 0, stream>>>(A2, out_w, out_b, A5, DOUTD, nullptr, nullptr);
    // --- VQ ---
    c2_k<<<NE / 256, 256, 0, stream>>>(cb, c2v);
    hipMemsetAsync(counts, 0, NE * sizeof(int), stream);
    vq_k<<<(BROWS * 4) / 256, 256, 0, stream>>>(A5, cb, c2v, A3, dout + O_IDX, counts, partials);
    copy_k<<<(BROWS * DOUTD) / 256, 256, 0, stream>>>(A3, dout + O_ZQ, BROWS * DOUTD);
    fin_k<<<1, 256, 0, stream>>>(partials, counts, dout, dout + O_PERP);
    // --- decoder ---
    gemm_k<256, 0><<<dim3(DE / 64, BROWS / 64), 256, 0, stream>>>(A3, dec1_w, dec1_b, A1, DE, nullptr, nullptr);
    for (int r = 0; r < 3; ++r) {
        gemm_k<512, 0><<<dim3(DE / 64, BROWS / 64), 256, 0, stream>>>(A1, dres_w, dres_b, A2, DE, nullptr, nullptr);
        ln_dec_k<<<BROWS / 4, 256, 0, stream>>>(A2, A1, dres_g, dres_be);
    }
    gemm_k<512, 1><<<dim3(IND / 64, BROWS / 64), 256, 0, stream>>>(A1, dec2_w, dec2_b, dout + O_XHAT, IND, scale, shift);
}

// Round 2
// 1240.976 us; speedup vs baseline: 1.6103x; 1.6103x over previous
//
#include <hip/hip_runtime.h>
#include <hip/hip_bf16.h>
#include <math.h>

static constexpr int BROWS = 16384;
static constexpr int IND   = 128;
static constexpr int DE    = 512;   // DENC
static constexpr int DOUTD = 256;   // dim_encoder_out
static constexpr int ED    = 64;    // codebook dim
static constexpr int NE    = 1024;  // codebook entries

// d_out layout (floats): [0]=loss, [1..]=x_hat(16384x128), [O_PERP]=perplexity,
// [O_ZQ..]=z_q_st(16384x256), [O_IDX..]=idx(65536)
static constexpr size_t O_XHAT = 1;
static constexpr size_t O_PERP = 2097153;
static constexpr size_t O_ZQ   = 2097154;
static constexpr size_t O_IDX  = 6291458;

typedef __attribute__((ext_vector_type(8))) short short8v;
typedef __attribute__((ext_vector_type(4))) float f32x4;

__device__ inline float wave_sum(float v) {
#pragma unroll
    for (int o = 32; o >= 1; o >>= 1) v += __shfl_xor(v, o, 64);
    return v;
}

// ---------------- fp32 GEMM v2: C[M][N] = A[M][K] @ W[N][K]^T + bias --------------------
// 128x128 tile, 256 threads, 8x8 microtile. Per-output FMA chain is k-ascending
// (bitwise identical to round-1 kernel -> z_e / idx unchanged).
template<int K>
__global__ __launch_bounds__(256)
void gemm32_k(const float* __restrict__ A, const float* __restrict__ W,
              const float* __restrict__ bias, float* __restrict__ C, int N)
{
    __shared__ float As[32 * 132];
    __shared__ float Ws[32 * 132];
    const int t = threadIdx.x;
    const int bm = blockIdx.y << 7, bn = blockIdx.x << 7;
    const int tx = t & 15, ty = t >> 4;
    float acc[8][8] = {};
    for (int k0 = 0; k0 < K; k0 += 32) {
#pragma unroll
        for (int s = 0; s < 4; ++s) {
            int c = t + (s << 8);
            int row = c >> 3, kc = (c & 7) << 2;
            float4 va = *(const float4*)(A + (size_t)(bm + row) * K + k0 + kc);
            As[(kc + 0) * 132 + row] = va.x; As[(kc + 1) * 132 + row] = va.y;
            As[(kc + 2) * 132 + row] = va.z; As[(kc + 3) * 132 + row] = va.w;
            float4 vw = *(const float4*)(W + (size_t)(bn + row) * K + k0 + kc);
            Ws[(kc + 0) * 132 + row] = vw.x; Ws[(kc + 1) * 132 + row] = vw.y;
            Ws[(kc + 2) * 132 + row] = vw.z; Ws[(kc + 3) * 132 + row] = vw.w;
        }
        __syncthreads();
#pragma unroll 8
        for (int kk = 0; kk < 32; ++kk) {
            float a[8], b[8];
            *(float4*)&a[0] = *(const float4*)&As[kk * 132 + (ty << 3)];
            *(float4*)&a[4] = *(const float4*)&As[kk * 132 + (ty << 3) + 4];
            *(float4*)&b[0] = *(const float4*)&Ws[kk * 132 + (tx << 3)];
            *(float4*)&b[4] = *(const float4*)&Ws[kk * 132 + (tx << 3) + 4];
#pragma unroll
            for (int i = 0; i < 8; ++i)
#pragma unroll
                for (int j = 0; j < 8; ++j)
                    acc[i][j] = fmaf(a[i], b[j], acc[i][j]);
        }
        __syncthreads();
    }
#pragma unroll
    for (int i = 0; i < 8; ++i) {
        int m = bm + (ty << 3) + i;
#pragma unroll
        for (int j = 0; j < 8; ++j) {
            int n = bn + (tx << 3) + j;
            C[(size_t)m * N + n] = acc[i][j] + bias[n];
        }
    }
}

// ---------------- bf16 MFMA GEMM (decoder only): C = A @ W^T + bias ---------------------
// EPI: 0 = fp32 C only; 1 = fp32 C + bf16 Cb; 2 = scale*v+shift into C.
template<int K, int EPI>
__global__ __launch_bounds__(256)
void gemmbf_k(const short* __restrict__ A, const short* __restrict__ W,
              const float* __restrict__ bias, float* __restrict__ C, int N,
              __hip_bfloat16* __restrict__ Cb,
              const float* __restrict__ escale, const float* __restrict__ eshift)
{
    __shared__ short As[128 * 40];
    __shared__ short Ws[128 * 40];
    const int t = threadIdx.x;
    const int bm = blockIdx.y << 7, bn = blockIdx.x << 7;
    const int lane = t & 63, wid = t >> 6;
    const int wm = (wid >> 1) << 6, wn = (wid & 1) << 6;
    const int lr = lane & 15, lg = lane >> 4;
    f32x4 acc[4][4] = {};
    for (int k0 = 0; k0 < K; k0 += 32) {
#pragma unroll
        for (int s = 0; s < 2; ++s) {
            int c = t + (s << 8);
            int row = c >> 2, kc = (c & 3) << 3;
            *(short8v*)&As[row * 40 + kc] = *(const short8v*)(A + (size_t)(bm + row) * K + k0 + kc);
            *(short8v*)&Ws[row * 40 + kc] = *(const short8v*)(W + (size_t)(bn + row) * K + k0 + kc);
        }
        __syncthreads();
        short8v af[4], bf[4];
#pragma unroll
        for (int mi = 0; mi < 4; ++mi) af[mi] = *(const short8v*)&As[(wm + mi * 16 + lr) * 40 + lg * 8];
#pragma unroll
        for (int nj = 0; nj < 4; ++nj) bf[nj] = *(const short8v*)&Ws[(wn + nj * 16 + lr) * 40 + lg * 8];
#pragma unroll
        for (int mi = 0; mi < 4; ++mi)
#pragma unroll
            for (int nj = 0; nj < 4; ++nj)
                acc[mi][nj] = __builtin_amdgcn_mfma_f32_16x16x32_bf16(af[mi], bf[nj], acc[mi][nj], 0, 0, 0);
        __syncthreads();
    }
#pragma unroll
    for (int mi = 0; mi < 4; ++mi) {
#pragma unroll
        for (int nj = 0; nj < 4; ++nj) {
#pragma unroll
            for (int r = 0; r < 4; ++r) {
                int m = bm + wm + mi * 16 + lg * 4 + r;
                int n = bn + wn + nj * 16 + lr;
                float v = acc[mi][nj][r] + bias[n];
                if (EPI == 2) v = escale[n] * v + eshift[n];
                C[(size_t)m * N + n] = v;
                if (EPI == 1) Cb[(size_t)m * N + n] = __float2bfloat16(v);
            }
        }
    }
}

// -------------- input normalization: xs = (x - shift) / scale ---------------------------
__global__ __launch_bounds__(256)
void prep_k(const float* __restrict__ x, const float* __restrict__ scale,
            const float* __restrict__ shift, float* __restrict__ xs)
{
    int g = blockIdx.x * 256 + threadIdx.x;
    int col = g & (IND - 1);
    xs[g] = (x[g] - shift[col]) / scale[col];
}

// -------------- fp32 -> bf16 convert -----------------------------------------------------
__global__ __launch_bounds__(256)
void cvt_k(const float* __restrict__ src, __hip_bfloat16* __restrict__ dst, int n)
{
    int g = blockIdx.x * 256 + threadIdx.x;
    if (g < n) dst[g] = __float2bfloat16(src[g]);
}

// -------------- fused encoder resblock tail ---------------------------------------------
__global__ __launch_bounds__(256)
void ln_enc_k(const float* __restrict__ tav, const float* __restrict__ th,
              float* __restrict__ av, float* __restrict__ h,
              const float* __restrict__ ag, const float* __restrict__ abe,
              const float* __restrict__ wg, const float* __restrict__ wbe)
{
    const int lane = threadIdx.x & 63;
    const int row  = (blockIdx.x << 2) + (threadIdx.x >> 6);
    const int col  = lane << 3;
    const size_t base = (size_t)row * DE + col;

    float t[8];
    { float4 p0 = *(const float4*)(tav + base); float4 p1 = *(const float4*)(tav + base + 4);
      t[0]=p0.x; t[1]=p0.y; t[2]=p0.z; t[3]=p0.w; t[4]=p1.x; t[5]=p1.y; t[6]=p1.z; t[7]=p1.w; }
    float s = 0.f;
#pragma unroll
    for (int i = 0; i < 8; ++i) s += t[i];
    s = wave_sum(s);
    float mean = s * (1.0f / 512.0f);
    float vs = 0.f;
#pragma unroll
    for (int i = 0; i < 8; ++i) { float d = t[i] - mean; vs += d * d; }
    vs = wave_sum(vs);
    float rstd = 1.0f / sqrtf(vs * (1.0f / 512.0f) + 1e-5f);

    float avn[8];
    { float4 p0 = *(const float4*)(av + base); float4 p1 = *(const float4*)(av + base + 4);
      float avv[8] = {p0.x,p0.y,p0.z,p0.w,p1.x,p1.y,p1.z,p1.w};
#pragma unroll
      for (int i = 0; i < 8; ++i) {
          float lnv = (t[i] - mean) * rstd * ag[col + i] + abe[col + i];
          avn[i] = avv[i] + fmaxf(lnv, 0.0f);
      }
      float4 o0 = {avn[0],avn[1],avn[2],avn[3]}, o1 = {avn[4],avn[5],avn[6],avn[7]};
      *(float4*)(av + base) = o0; *(float4*)(av + base + 4) = o1; }

    { float4 p0 = *(const float4*)(th + base); float4 p1 = *(const float4*)(th + base + 4);
      t[0]=p0.x; t[1]=p0.y; t[2]=p0.z; t[3]=p0.w; t[4]=p1.x; t[5]=p1.y; t[6]=p1.z; t[7]=p1.w; }
    s = 0.f;
#pragma unroll
    for (int i = 0; i < 8; ++i) s += t[i];
    s = wave_sum(s);
    float mean2 = s * (1.0f / 512.0f);
    vs = 0.f;
#pragma unroll
    for (int i = 0; i < 8; ++i) { float d = t[i] - mean2; vs += d * d; }
    vs = wave_sum(vs);
    float rstd2 = 1.0f / sqrtf(vs * (1.0f / 512.0f) + 1e-5f);
    { float4 p0 = *(const float4*)(h + base); float4 p1 = *(const float4*)(h + base + 4);
      float hv[8] = {p0.x,p0.y,p0.z,p0.w,p1.x,p1.y,p1.z,p1.w};
      float hn[8];
#pragma unroll
      for (int i = 0; i < 8; ++i) {
          float lnv = (t[i] - mean2) * rstd2 * wg[col + i] + wbe[col + i];
          hn[i] = (hv[i] + fmaxf(lnv, 0.0f)) * avn[i];
      }
      float4 o0 = {hn[0],hn[1],hn[2],hn[3]}, o1 = {hn[4],hn[5],hn[6],hn[7]};
      *(float4*)(h + base) = o0; *(float4*)(h + base + 4) = o1; }
}

// -------------- decoder resblock tail: h = h + relu(ln(t)); emits bf16 of h -------------
__global__ __launch_bounds__(256)
void ln_dec_k(const float* __restrict__ t_, float* __restrict__ h,
              const float* __restrict__ g, const float* __restrict__ be,
              __hip_bfloat16* __restrict__ hb)
{
    const int lane = threadIdx.x & 63;
    const int row  = (blockIdx.x << 2) + (threadIdx.x >> 6);
    const int col  = lane << 3;
    const size_t base = (size_t)row * DE + col;
    float t[8];
    { float4 p0 = *(const float4*)(t_ + base); float4 p1 = *(const float4*)(t_ + base + 4);
      t[0]=p0.x; t[1]=p0.y; t[2]=p0.z; t[3]=p0.w; t[4]=p1.x; t[5]=p1.y; t[6]=p1.z; t[7]=p1.w; }
    float s = 0.f;
#pragma unroll
    for (int i = 0; i < 8; ++i) s += t[i];
    s = wave_sum(s);
    float mean = s * (1.0f / 512.0f);
    float vs = 0.f;
#pragma unroll
    for (int i = 0; i < 8; ++i) { float d = t[i] - mean; vs += d * d; }
    vs = wave_sum(vs);
    float rstd = 1.0f / sqrtf(vs * (1.0f / 512.0f) + 1e-5f);
    { float4 p0 = *(const float4*)(h + base); float4 p1 = *(const float4*)(h + base + 4);
      float hv[8] = {p0.x,p0.y,p0.z,p0.w,p1.x,p1.y,p1.z,p1.w};
      float hn[8];
#pragma unroll
      for (int i = 0; i < 8; ++i) {
          float lnv = (t[i] - mean) * rstd * g[col + i] + be[col + i];
          hn[i] = hv[i] + fmaxf(lnv, 0.0f);
      }
      float4 o0 = {hn[0],hn[1],hn[2],hn[3]}, o1 = {hn[4],hn[5],hn[6],hn[7]};
      *(float4*)(h + base) = o0; *(float4*)(h + base + 4) = o1;
#pragma unroll
      for (int i = 0; i < 8; ++i) hb[base + i] = __float2bfloat16(hn[i]);
    }
}

// -------------- codebook squared norms --------------------------------------------------
__global__ __launch_bounds__(256)
void c2_k(const float* __restrict__ cb, float* __restrict__ c2)
{
    int j = blockIdx.x * 256 + threadIdx.x;
    if (j < NE) {
        float s = 0.f;
        const float* p = cb + (size_t)j * ED;
#pragma unroll
        for (int d = 0; d < ED; ++d) s = fmaf(p[d], p[d], s);
        c2[j] = s;
    }
}

// -------------- VQ v2: register-blocked distance GEMM + argmin ---------------------------
// Block: 64 rows x all 1024 codes. 256 threads; per-thread 4 rows x 8 codes microtile.
// FMA chain per (row,code) is k-ascending -> bitwise identical distances to round-1.
__global__ __launch_bounds__(256)
void vq_k(const float* __restrict__ ze, const float* __restrict__ cb, const float* __restrict__ c2,
          float* __restrict__ idx_dst, float* __restrict__ zst_dst,
          __hip_bfloat16* __restrict__ zb,
          int* __restrict__ counts, float* __restrict__ partials)
{
    __shared__ float zs[64 * 68];     // [d][row]
    __shared__ float cbs[64 * 132];   // [d][code] (aliased for reduction at the end)
    __shared__ float z2s[64];
    __shared__ float c2s[128];
    __shared__ int   bidxs[64];
    __shared__ float red[4];
    const int t = threadIdx.x;
    const int tx = t & 15, ty = t >> 4;
    const size_t row0 = (size_t)blockIdx.x * 64;

    // stage z tile transposed
#pragma unroll
    for (int s = 0; s < 4; ++s) {
        int c = t + (s << 8);
        int row = c >> 4, dc = (c & 15) << 2;
        float4 v = *(const float4*)(ze + (row0 + row) * 64 + dc);
        zs[(dc + 0) * 68 + row] = v.x; zs[(dc + 1) * 68 + row] = v.y;
        zs[(dc + 2) * 68 + row] = v.z; zs[(dc + 3) * 68 + row] = v.w;
    }
    __syncthreads();
    if (t < 64) {
        float z2 = 0.f;
#pragma unroll 8
        for (int d = 0; d < 64; ++d) { float zv = zs[d * 68 + t]; z2 = fmaf(zv, zv, z2); }
        z2s[t] = z2;
    }

    float best[4] = {INFINITY, INFINITY, INFINITY, INFINITY};
    int   bid[4]  = {0, 0, 0, 0};
    for (int t0 = 0; t0 < NE; t0 += 128) {
        __syncthreads();
#pragma unroll
        for (int s = 0; s < 8; ++s) {
            int c = t + (s << 8);
            int code = c >> 4, dc = (c & 15) << 2;
            float4 v = *(const float4*)(cb + (size_t)(t0 + code) * 64 + dc);
            cbs[(dc + 0) * 132 + code] = v.x; cbs[(dc + 1) * 132 + code] = v.y;
            cbs[(dc + 2) * 132 + code] = v.z; cbs[(dc + 3) * 132 + code] = v.w;
        }
        if (t < 128) c2s[t] = c2[t0 + t];
        __syncthreads();
        float acc[4][8] = {};
#pragma unroll 8
        for (int kk = 0; kk < 64; ++kk) {
            float4 a = *(const float4*)&zs[kk * 68 + (ty << 2)];
            float4 b0 = *(const float4*)&cbs[kk * 132 + (tx << 3)];
            float4 b1 = *(const float4*)&cbs[kk * 132 + (tx << 3) + 4];
            float av_[4] = {a.x, a.y, a.z, a.w};
            float bv_[8] = {b0.x, b0.y, b0.z, b0.w, b1.x, b1.y, b1.z, b1.w};
#pragma unroll
            for (int r = 0; r < 4; ++r)
#pragma unroll
                for (int j = 0; j < 8; ++j)
                    acc[r][j] = fmaf(av_[r], bv_[j], acc[r][j]);
        }
#pragma unroll
        for (int r = 0; r < 4; ++r) {
            float z2v = z2s[(ty << 2) + r];
#pragma unroll
            for (int j = 0; j < 8; ++j) {
                float term = __fadd_rn(z2v, c2s[(tx << 3) + j]);
                float dist = __fsub_rn(term, __fmul_rn(2.0f, acc[r][j]));
                if (dist < best[r]) { best[r] = dist; bid[r] = t0 + (tx << 3) + j; }
            }
        }
    }
    __syncthreads();
    float* rbd = cbs;              // alias: reduction scratch
    int*   rbi = (int*)(cbs + 1024);
#pragma unroll
    for (int r = 0; r < 4; ++r) {
        rbd[((ty << 2) + r) * 16 + tx] = best[r];
        rbi[((ty << 2) + r) * 16 + tx] = bid[r];
    }
    __syncthreads();
    if (t < 64) {
        float bd = INFINITY; int bi = 0;
#pragma unroll
        for (int q = 0; q < 16; ++q) {
            float d = rbd[t * 16 + q]; int i = rbi[t * 16 + q];
            if (d < bd || (d == bd && i < bi)) { bd = d; bi = i; }
        }
        bidxs[t] = bi;
        idx_dst[row0 + t] = (float)bi;
        atomicAdd(&counts[bi], 1);
    }
    __syncthreads();
    // epilogue: z_q_st + bf16 + loss partial
    const int row = t >> 2, cq = t & 3;
    const int bi = bidxs[row];
    float lsum = 0.f;
#pragma unroll
    for (int dd = 0; dd < 16; dd += 4) {
        int d0 = (cq << 4) + dd;
        float4 q4 = *(const float4*)(cb + (size_t)bi * 64 + d0);
        float qv[4] = {q4.x, q4.y, q4.z, q4.w};
        float zst[4];
#pragma unroll
        for (int i = 0; i < 4; ++i) {
            float zv = zs[(d0 + i) * 68 + row];
            float df = qv[i] - zv;
            lsum = fmaf(df, df, lsum);
            zst[i] = __fadd_rn(zv, __fsub_rn(qv[i], zv));
            zb[(row0 + row) * 64 + d0 + i] = __float2bfloat16(zst[i]);
        }
        float2 o0 = {zst[0], zst[1]}, o1 = {zst[2], zst[3]};
        *(float2*)(zst_dst + (row0 + row) * 64 + d0) = o0;
        *(float2*)(zst_dst + (row0 + row) * 64 + d0 + 2) = o1;
    }
    lsum = wave_sum(lsum);
    if ((t & 63) == 0) red[t >> 6] = lsum;
    __syncthreads();
    if (t == 0) partials[blockIdx.x] = ((red[0] + red[1]) + red[2]) + red[3];
}

// -------------- finalize: loss + perplexity ---------------------------------------------
__global__ __launch_bounds__(256)
void fin_k(const float* __restrict__ partials, const int* __restrict__ counts,
           float* __restrict__ loss_out, float* __restrict__ perp_out)
{
    __shared__ float red[4];
    __shared__ float red2[4];
    const int tid = threadIdx.x;
    float v = 0.f;
    for (int c = tid; c < 1024; c += 256) v += partials[c];
    float s = wave_sum(v);
    if ((tid & 63) == 0) red[tid >> 6] = s;
    float ep = 0.f;
    for (int c = tid; c < NE; c += 256) {
        float e = (float)counts[c] * (1.0f / 65536.0f);
        ep += e * logf(e + 1e-10f);
    }
    ep = wave_sum(ep);
    if ((tid & 63) == 0) red2[tid >> 6] = ep;
    __syncthreads();
    if (tid == 0) {
        float S = ((red[0] + red[1]) + red[2]) + red[3];
        float E = ((red2[0] + red2[1]) + red2[2]) + red2[3];
        loss_out[0] = 1.25f * (S * (1.0f / 4194304.0f));
        perp_out[0] = expf(-E);
    }
}

extern "C" void kernel_launch(void* const* d_in, const int* in_sizes, int n_in,
                              void* d_out, int out_size, void* d_ws, size_t ws_size,
                              hipStream_t stream)
{
    const float* x       = (const float*)d_in[0];
    const float* a       = (const float*)d_in[1];
    const float* scale   = (const float*)d_in[2];
    const float* shift   = (const float*)d_in[3];
    const float* win_w   = (const float*)d_in[4];
    const float* win_b   = (const float*)d_in[5];
    const float* ain_w   = (const float*)d_in[6];
    const float* ain_b   = (const float*)d_in[7];
    const float* wres_w  = (const float*)d_in[8];
    const float* wres_b  = (const float*)d_in[9];
    const float* wres_g  = (const float*)d_in[10];
    const float* wres_be = (const float*)d_in[11];
    const float* ares_w  = (const float*)d_in[12];
    const float* ares_b  = (const float*)d_in[13];
    const float* ares_g  = (const float*)d_in[14];
    const float* ares_be = (const float*)d_in[15];
    const float* out_w   = (const float*)d_in[16];
    const float* out_b   = (const float*)d_in[17];
    const float* dec1_w  = (const float*)d_in[18];
    const float* dec1_b  = (const float*)d_in[19];
    const float* dres_w  = (const float*)d_in[20];
    const float* dres_b  = (const float*)d_in[21];
    const float* dres_g  = (const float*)d_in[22];
    const float* dres_be = (const float*)d_in[23];
    const float* dec2_w  = (const float*)d_in[24];
    const float* dec2_b  = (const float*)d_in[25];
    const float* cb      = (const float*)d_in[26];

    float* ws = (float*)d_ws;
    const size_t SZ_BD = (size_t)BROWS * DE;
    float* A1 = ws;                // av  -> hd (decoder, fp32 master)
    float* A2 = A1 + SZ_BD;        // h   -> t (decoder)
    float* A3 = A2 + SZ_BD;        // xs -> t_av (enc) -> Hb bf16 (decoder)
    float* A4 = A3 + SZ_BD;        // t_h (enc) -> Zb bf16 + bf16 weights (decoder)
    float* A5 = A4 + SZ_BD;        // z_e
    float* SMALL = A5 + (size_t)BROWS * DOUTD;
    float* c2v      = SMALL;
    int*   counts   = (int*)(SMALL + 1024);
    float* partials = SMALL + 2048;            // 1024 entries

    __hip_bfloat16* Hb  = (__hip_bfloat16*)A3;
    __hip_bfloat16* Zb  = (__hip_bfloat16*)A4;                    // 65536*64 bf16 = 4.19M floats
    __hip_bfloat16* w1b = (__hip_bfloat16*)(A4 + 4194304);        // 512x256
    __hip_bfloat16* wrb = (__hip_bfloat16*)(A4 + 4194304 + 65536);// 512x512
    __hip_bfloat16* w2b = (__hip_bfloat16*)(A4 + 4194304 + 65536 + 131072); // 128x512

    float* dout = (float*)d_out;

    // --- encoder (pure fp32, bitwise identical to passing round-1 kernel) ---
    prep_k<<<(BROWS * IND) / 256, 256, 0, stream>>>(x, scale, shift, A3);
    gemm32_k<128><<<dim3(DE / 128, BROWS / 128), 256, 0, stream>>>(a,  ain_w, ain_b, A1, DE);
    gemm32_k<128><<<dim3(DE / 128, BROWS / 128), 256, 0, stream>>>(A3, win_w, win_b, A2, DE);
    for (int r = 0; r < 3; ++r) {
        gemm32_k<512><<<dim3(DE / 128, BROWS / 128), 256, 0, stream>>>(A1, ares_w, ares_b, A3, DE);
        gemm32_k<512><<<dim3(DE / 128, BROWS / 128), 256, 0, stream>>>(A2, wres_w, wres_b, A4, DE);
        ln_enc_k<<<BROWS / 4, 256, 0, stream>>>(A3, A4, A1, A2, ares_g, ares_be, wres_g, wres_be);
    }
    gemm32_k<512><<<dim3(DOUTD / 128, BROWS / 128), 256, 0, stream>>>(A2, out_w, out_b, A5, DOUTD);
    // --- VQ ---
    c2_k<<<NE / 256, 256, 0, stream>>>(cb, c2v);
    hipMemsetAsync(counts, 0, NE * sizeof(int), stream);
    vq_k<<<(BROWS * 4) / 64, 256, 0, stream>>>(A5, cb, c2v, dout + O_IDX, dout + O_ZQ, Zb, counts, partials);
    fin_k<<<1, 256, 0, stream>>>(partials, counts, dout, dout + O_PERP);
    // --- decoder (bf16 MFMA; only feeds x_hat, loose threshold) ---
    cvt_k<<<(DE * DOUTD + 255) / 256, 256, 0, stream>>>(dec1_w, w1b, DE * DOUTD);
    cvt_k<<<(DE * DE + 255) / 256, 256, 0, stream>>>(dres_w, wrb, DE * DE);
    cvt_k<<<(IND * DE + 255) / 256, 256, 0, stream>>>(dec2_w, w2b, IND * DE);
    gemmbf_k<256, 1><<<dim3(DE / 128, BROWS / 128), 256, 0, stream>>>(
        (const short*)Zb, (const short*)w1b, dec1_b, A1, DE, Hb, nullptr, nullptr);
    for (int r = 0; r < 3; ++r) {
        gemmbf_k<512, 0><<<dim3(DE / 128, BROWS / 128), 256, 0, stream>>>(
            (const short*)Hb, (const short*)wrb, dres_b, A2, DE, nullptr, nullptr, nullptr);
        ln_dec_k<<<BROWS / 4, 256, 0, stream>>>(A2, A1, dres_g, dres_be, Hb);
    }
    gemmbf_k<512, 2><<<dim3(IND / 128, BROWS / 128), 256, 0, stream>>>(
        (const short*)Hb, (const short*)w2b, dec2_b, dout + O_XHAT, IND, nullptr, scale, shift);
}

// Round 5
// 947.772 us; speedup vs baseline: 2.1085x; 1.3094x over previous
//
#include <hip/hip_runtime.h>
#include <hip/hip_bf16.h>
#include <math.h>

static constexpr int BROWS = 16384;
static constexpr int IND   = 128;
static constexpr int DE    = 512;
static constexpr int DOUTD = 256;
static constexpr int ED    = 64;
static constexpr int NE    = 1024;

static constexpr size_t O_XHAT = 1;
static constexpr size_t O_PERP = 2097153;
static constexpr size_t O_ZQ   = 2097154;
static constexpr size_t O_IDX  = 6291458;

typedef __attribute__((ext_vector_type(8))) short short8v;
typedef __attribute__((ext_vector_type(4))) float f32x4;
typedef __attribute__((ext_vector_type(4))) unsigned short ushort4v;
typedef __attribute__((ext_vector_type(8))) unsigned short ushort8v;

__device__ inline float wave_sum(float v) {
#pragma unroll
    for (int o = 32; o >= 1; o >>= 1) v += __shfl_xor(v, o, 64);
    return v;
}

__device__ inline unsigned short f2bf(float f) {
    unsigned u = __float_as_uint(f);
    return (unsigned short)((u + 0x7FFFu + ((u >> 16) & 1u)) >> 16);
}
__device__ inline float bf2f(unsigned short b) {
    return __uint_as_float(((unsigned)b) << 16);
}
struct Split3 { unsigned short b0, b1, b2; };
__device__ inline Split3 split3(float v) {
    Split3 s;
    s.b0 = f2bf(v);  float r  = v - bf2f(s.b0);
    s.b1 = f2bf(r);  float r2 = r - bf2f(s.b1);
    s.b2 = f2bf(r2);
    return s;
}

// ---------------- 8-term split-bf16 MFMA GEMM: C = A@W^T + bias (fp32-accurate) ---------
// A = A0+A1+A2, W = W0+W1+W2 (bf16 splits). Only a2*b2 dropped (<=2^-36 rel; K-coherent
// bound 2^-27 — 100x below fp32-chain noise which passes). Smallest terms accumulated first.
template<int K>
__global__ __launch_bounds__(256)
void gemm8_k(const unsigned short* __restrict__ A0, const unsigned short* __restrict__ A1,
             const unsigned short* __restrict__ A2,
             const unsigned short* __restrict__ W0, const unsigned short* __restrict__ W1,
             const unsigned short* __restrict__ W2,
             const float* __restrict__ bias, float* __restrict__ C, int N)
{
    __shared__ short As[3][128 * 40];
    __shared__ short Ws[3][128 * 40];
    const int t = threadIdx.x;
    const int bm = blockIdx.y << 7, bn = blockIdx.x << 7;
    const int lane = t & 63, wid = t >> 6;
    const int wm = (wid >> 1) << 6, wn = (wid & 1) << 6;
    const int lr = lane & 15, lg = lane >> 4;
    const unsigned short* Ap[3] = {A0, A1, A2};
    const unsigned short* Wp[3] = {W0, W1, W2};
    f32x4 acc[4][4] = {};
    for (int k0 = 0; k0 < K; k0 += 32) {
#pragma unroll
        for (int p = 0; p < 3; ++p) {
#pragma unroll
            for (int s = 0; s < 2; ++s) {
                int c = t + (s << 8);
                int row = c >> 2, kc = (c & 3) << 3;
                *(short8v*)&As[p][row * 40 + kc] =
                    *(const short8v*)(Ap[p] + (size_t)(bm + row) * K + k0 + kc);
                *(short8v*)&Ws[p][row * 40 + kc] =
                    *(const short8v*)(Wp[p] + (size_t)(bn + row) * K + k0 + kc);
            }
        }
        __syncthreads();
        short8v bfr[3][4];
#pragma unroll
        for (int p = 0; p < 3; ++p)
#pragma unroll
            for (int nj = 0; nj < 4; ++nj)
                bfr[p][nj] = *(const short8v*)&Ws[p][(wn + nj * 16 + lr) * 40 + lg * 8];
#pragma unroll
        for (int mi = 0; mi < 4; ++mi) {
            short8v a0 = *(const short8v*)&As[0][(wm + mi * 16 + lr) * 40 + lg * 8];
            short8v a1 = *(const short8v*)&As[1][(wm + mi * 16 + lr) * 40 + lg * 8];
            short8v a2 = *(const short8v*)&As[2][(wm + mi * 16 + lr) * 40 + lg * 8];
#pragma unroll
            for (int nj = 0; nj < 4; ++nj) {
                f32x4 c = acc[mi][nj];
                c = __builtin_amdgcn_mfma_f32_16x16x32_bf16(a2, bfr[1][nj], c, 0, 0, 0);
                c = __builtin_amdgcn_mfma_f32_16x16x32_bf16(a1, bfr[2][nj], c, 0, 0, 0);
                c = __builtin_amdgcn_mfma_f32_16x16x32_bf16(a1, bfr[1][nj], c, 0, 0, 0);
                c = __builtin_amdgcn_mfma_f32_16x16x32_bf16(a2, bfr[0][nj], c, 0, 0, 0);
                c = __builtin_amdgcn_mfma_f32_16x16x32_bf16(a0, bfr[2][nj], c, 0, 0, 0);
                c = __builtin_amdgcn_mfma_f32_16x16x32_bf16(a1, bfr[0][nj], c, 0, 0, 0);
                c = __builtin_amdgcn_mfma_f32_16x16x32_bf16(a0, bfr[1][nj], c, 0, 0, 0);
                c = __builtin_amdgcn_mfma_f32_16x16x32_bf16(a0, bfr[0][nj], c, 0, 0, 0);
                acc[mi][nj] = c;
            }
        }
        __syncthreads();
    }
#pragma unroll
    for (int mi = 0; mi < 4; ++mi)
#pragma unroll
        for (int nj = 0; nj < 4; ++nj)
#pragma unroll
            for (int r = 0; r < 4; ++r) {
                int m = bm + wm + mi * 16 + lg * 4 + r;
                int n = bn + wn + nj * 16 + lr;
                C[(size_t)m * N + n] = acc[mi][nj][r] + bias[n];
            }
}

// ---------------- bf16 MFMA GEMM (decoder): C = A@W^T + bias ----------------------------
template<int K, int EPI>
__global__ __launch_bounds__(256)
void gemmbf_k(const short* __restrict__ A, const short* __restrict__ W,
              const float* __restrict__ bias, float* __restrict__ C, int N,
              unsigned short* __restrict__ Cb,
              const float* __restrict__ escale, const float* __restrict__ eshift)
{
    __shared__ short As[128 * 40];
    __shared__ short Ws[128 * 40];
    const int t = threadIdx.x;
    const int bm = blockIdx.y << 7, bn = blockIdx.x << 7;
    const int lane = t & 63, wid = t >> 6;
    const int wm = (wid >> 1) << 6, wn = (wid & 1) << 6;
    const int lr = lane & 15, lg = lane >> 4;
    f32x4 acc[4][4] = {};
    for (int k0 = 0; k0 < K; k0 += 32) {
#pragma unroll
        for (int s = 0; s < 2; ++s) {
            int c = t + (s << 8);
            int row = c >> 2, kc = (c & 3) << 3;
            *(short8v*)&As[row * 40 + kc] = *(const short8v*)(A + (size_t)(bm + row) * K + k0 + kc);
            *(short8v*)&Ws[row * 40 + kc] = *(const short8v*)(W + (size_t)(bn + row) * K + k0 + kc);
        }
        __syncthreads();
        short8v af[4], bf[4];
#pragma unroll
        for (int mi = 0; mi < 4; ++mi) af[mi] = *(const short8v*)&As[(wm + mi * 16 + lr) * 40 + lg * 8];
#pragma unroll
        for (int nj = 0; nj < 4; ++nj) bf[nj] = *(const short8v*)&Ws[(wn + nj * 16 + lr) * 40 + lg * 8];
#pragma unroll
        for (int mi = 0; mi < 4; ++mi)
#pragma unroll
            for (int nj = 0; nj < 4; ++nj)
                acc[mi][nj] = __builtin_amdgcn_mfma_f32_16x16x32_bf16(af[mi], bf[nj], acc[mi][nj], 0, 0, 0);
        __syncthreads();
    }
#pragma unroll
    for (int mi = 0; mi < 4; ++mi)
#pragma unroll
        for (int nj = 0; nj < 4; ++nj)
#pragma unroll
            for (int r = 0; r < 4; ++r) {
                int m = bm + wm + mi * 16 + lg * 4 + r;
                int n = bn + wn + nj * 16 + lr;
                float v = acc[mi][nj][r] + bias[n];
                if (EPI == 2) v = escale[n] * v + eshift[n];
                C[(size_t)m * N + n] = v;
                if (EPI == 1) Cb[(size_t)m * N + n] = f2bf(v);
            }
}

// -------------- x -> xs splits (no fp32 xs kept) ----------------------------------------
__global__ __launch_bounds__(256)
void prep_split_k(const float* __restrict__ x, const float* __restrict__ scale,
                  const float* __restrict__ shift,
                  unsigned short* __restrict__ d0, unsigned short* __restrict__ d1,
                  unsigned short* __restrict__ d2)
{
    int g = blockIdx.x * 256 + threadIdx.x;           // float4 index
    float4 v = *(const float4*)(x + (size_t)g * 4);
    int col = (g * 4) & (IND - 1);
    float vals[4] = {v.x, v.y, v.z, v.w};
    ushort4v o0, o1, o2;
#pragma unroll
    for (int i = 0; i < 4; ++i) {
        float xs = (vals[i] - shift[col + i]) / scale[col + i];
        Split3 s = split3(xs);
        o0[i] = s.b0; o1[i] = s.b1; o2[i] = s.b2;
    }
    *(ushort4v*)(d0 + (size_t)g * 4) = o0;
    *(ushort4v*)(d1 + (size_t)g * 4) = o1;
    *(ushort4v*)(d2 + (size_t)g * 4) = o2;
}

// -------------- generic fp32 -> 3 bf16 splits -------------------------------------------
__global__ __launch_bounds__(256)
void split3_k(const float* __restrict__ src,
              unsigned short* __restrict__ d0, unsigned short* __restrict__ d1,
              unsigned short* __restrict__ d2, int n4)
{
    int g = blockIdx.x * 256 + threadIdx.x;
    if (g >= n4) return;
    float4 v = *(const float4*)(src + (size_t)g * 4);
    float vals[4] = {v.x, v.y, v.z, v.w};
    ushort4v o0, o1, o2;
#pragma unroll
    for (int i = 0; i < 4; ++i) {
        Split3 s = split3(vals[i]);
        o0[i] = s.b0; o1[i] = s.b1; o2[i] = s.b2;
    }
    *(ushort4v*)(d0 + (size_t)g * 4) = o0;
    *(ushort4v*)(d1 + (size_t)g * 4) = o1;
    *(ushort4v*)(d2 + (size_t)g * 4) = o2;
}

// -------------- fp32 -> bf16 (decoder weights) ------------------------------------------
__global__ __launch_bounds__(256)
void cvt_k(const float* __restrict__ src, unsigned short* __restrict__ dst, int n)
{
    int g = blockIdx.x * 256 + threadIdx.x;
    if (g < n) dst[g] = f2bf(src[g]);
}

// -------------- encoder av-resblock tail: av += relu(ln(T)); av kept as splits ----------
__global__ __launch_bounds__(256)
void ln_av_k(const float* __restrict__ T,
             unsigned short* __restrict__ s0, unsigned short* __restrict__ s1,
             unsigned short* __restrict__ s2,
             const float* __restrict__ g, const float* __restrict__ be)
{
    const int lane = threadIdx.x & 63;
    const int row  = (blockIdx.x << 2) + (threadIdx.x >> 6);
    const int col  = lane << 3;
    const size_t base = (size_t)row * DE + col;
    float t[8];
    { float4 p0 = *(const float4*)(T + base); float4 p1 = *(const float4*)(T + base + 4);
      t[0]=p0.x; t[1]=p0.y; t[2]=p0.z; t[3]=p0.w; t[4]=p1.x; t[5]=p1.y; t[6]=p1.z; t[7]=p1.w; }
    float s = 0.f;
#pragma unroll
    for (int i = 0; i < 8; ++i) s += t[i];
    s = wave_sum(s);
    float mean = s * (1.0f / 512.0f);
    float vs = 0.f;
#pragma unroll
    for (int i = 0; i < 8; ++i) { float d = t[i] - mean; vs += d * d; }
    vs = wave_sum(vs);
    float rstd = 1.0f / sqrtf(vs * (1.0f / 512.0f) + 1e-5f);
    ushort8v b0 = *(const ushort8v*)(s0 + base);
    ushort8v b1 = *(const ushort8v*)(s1 + base);
    ushort8v b2 = *(const ushort8v*)(s2 + base);
    ushort8v o0, o1, o2;
#pragma unroll
    for (int i = 0; i < 8; ++i) {
        float avv = bf2f(b0[i]) + bf2f(b1[i]) + bf2f(b2[i]);
        float lnv = (t[i] - mean) * rstd * g[col + i] + be[col + i];
        float avn = avv + fmaxf(lnv, 0.0f);
        Split3 sp = split3(avn);
        o0[i] = sp.b0; o1[i] = sp.b1; o2[i] = sp.b2;
    }
    *(ushort8v*)(s0 + base) = o0;
    *(ushort8v*)(s1 + base) = o1;
    *(ushort8v*)(s2 + base) = o2;
}

// -------------- encoder h-resblock tail: h = (h + relu(ln(T))) * av ---------------------
__global__ __launch_bounds__(256)
void ln_h_k(const float* __restrict__ T,
            unsigned short* __restrict__ s0, unsigned short* __restrict__ s1,
            unsigned short* __restrict__ s2,
            const unsigned short* __restrict__ a0, const unsigned short* __restrict__ a1,
            const unsigned short* __restrict__ a2,
            const float* __restrict__ g, const float* __restrict__ be)
{
    const int lane = threadIdx.x & 63;
    const int row  = (blockIdx.x << 2) + (threadIdx.x >> 6);
    const int col  = lane << 3;
    const size_t base = (size_t)row * DE + col;
    float t[8];
    { float4 p0 = *(const float4*)(T + base); float4 p1 = *(const float4*)(T + base + 4);
      t[0]=p0.x; t[1]=p0.y; t[2]=p0.z; t[3]=p0.w; t[4]=p1.x; t[5]=p1.y; t[6]=p1.z; t[7]=p1.w; }
    float s = 0.f;
#pragma unroll
    for (int i = 0; i < 8; ++i) s += t[i];
    s = wave_sum(s);
    float mean = s * (1.0f / 512.0f);
    float vs = 0.f;
#pragma unroll
    for (int i = 0; i < 8; ++i) { float d = t[i] - mean; vs += d * d; }
    vs = wave_sum(vs);
    float rstd = 1.0f / sqrtf(vs * (1.0f / 512.0f) + 1e-5f);
    ushort8v h0 = *(const ushort8v*)(s0 + base);
    ushort8v h1 = *(const ushort8v*)(s1 + base);
    ushort8v h2 = *(const ushort8v*)(s2 + base);
    ushort8v v0 = *(const ushort8v*)(a0 + base);
    ushort8v v1 = *(const ushort8v*)(a1 + base);
    ushort8v v2 = *(const ushort8v*)(a2 + base);
    ushort8v o0, o1, o2;
#pragma unroll
    for (int i = 0; i < 8; ++i) {
        float hv  = bf2f(h0[i]) + bf2f(h1[i]) + bf2f(h2[i]);
        float avn = bf2f(v0[i]) + bf2f(v1[i]) + bf2f(v2[i]);
        float lnv = (t[i] - mean) * rstd * g[col + i] + be[col + i];
        float hn  = (hv + fmaxf(lnv, 0.0f)) * avn;
        Split3 sp = split3(hn);
        o0[i] = sp.b0; o1[i] = sp.b1; o2[i] = sp.b2;
    }
    *(ushort8v*)(s0 + base) = o0;
    *(ushort8v*)(s1 + base) = o1;
    *(ushort8v*)(s2 + base) = o2;
}

// -------------- decoder resblock tail ---------------------------------------------------
__global__ __launch_bounds__(256)
void ln_dec_k(const float* __restrict__ t_, float* __restrict__ h,
              const float* __restrict__ g, const float* __restrict__ be,
              unsigned short* __restrict__ hb)
{
    const int lane = threadIdx.x & 63;
    const int row  = (blockIdx.x << 2) + (threadIdx.x >> 6);
    const int col  = lane << 3;
    const size_t base = (size_t)row * DE + col;
    float t[8];
    { float4 p0 = *(const float4*)(t_ + base); float4 p1 = *(const float4*)(t_ + base + 4);
      t[0]=p0.x; t[1]=p0.y; t[2]=p0.z; t[3]=p0.w; t[4]=p1.x; t[5]=p1.y; t[6]=p1.z; t[7]=p1.w; }
    float s = 0.f;
#pragma unroll
    for (int i = 0; i < 8; ++i) s += t[i];
    s = wave_sum(s);
    float mean = s * (1.0f / 512.0f);
    float vs = 0.f;
#pragma unroll
    for (int i = 0; i < 8; ++i) { float d = t[i] - mean; vs += d * d; }
    vs = wave_sum(vs);
    float rstd = 1.0f / sqrtf(vs * (1.0f / 512.0f) + 1e-5f);
    float4 p0 = *(const float4*)(h + base); float4 p1 = *(const float4*)(h + base + 4);
    float hv[8] = {p0.x,p0.y,p0.z,p0.w,p1.x,p1.y,p1.z,p1.w};
    float hn[8];
    ushort8v ob;
#pragma unroll
    for (int i = 0; i < 8; ++i) {
        float lnv = (t[i] - mean) * rstd * g[col + i] + be[col + i];
        hn[i] = hv[i] + fmaxf(lnv, 0.0f);
        ob[i] = f2bf(hn[i]);
    }
    float4 o0 = {hn[0],hn[1],hn[2],hn[3]}, o1 = {hn[4],hn[5],hn[6],hn[7]};
    *(float4*)(h + base) = o0; *(float4*)(h + base + 4) = o1;
    *(ushort8v*)(hb + base) = ob;
}

// -------------- codebook squared norms --------------------------------------------------
__global__ __launch_bounds__(256)
void c2_k(const float* __restrict__ cb, float* __restrict__ c2)
{
    int j = blockIdx.x * 256 + threadIdx.x;
    if (j < NE) {
        float s = 0.f;
        const float* p = cb + (size_t)j * ED;
#pragma unroll
        for (int d = 0; d < ED; ++d) s = fmaf(p[d], p[d], s);
        c2[j] = s;
    }
}

// -------------- VQ v3: conflict-free layouts, same bitwise distance chains --------------
__global__ __launch_bounds__(256)
void vq_k(const float* __restrict__ ze, const float* __restrict__ cb, const float* __restrict__ c2,
          float* __restrict__ idx_dst, float* __restrict__ zst_dst,
          unsigned short* __restrict__ zb,
          int* __restrict__ counts, float* __restrict__ partials)
{
    __shared__ float zs[64 * 68];     // [row][68]  row-major
    __shared__ float cbs[64 * 132];   // [d][code]  col-major (reduction scratch at end)
    __shared__ float z2s[64];
    __shared__ float c2s[128];
    __shared__ int   bidxs[64];
    __shared__ float red[4];
    const int t = threadIdx.x;
    const int tx = t & 15, ty = t >> 4;
    const size_t row0 = (size_t)blockIdx.x * 64;

#pragma unroll
    for (int s = 0; s < 4; ++s) {
        int c = t + (s << 8);
        int row = c >> 4, dc = (c & 15) << 2;
        float4 v = *(const float4*)(ze + (row0 + row) * 64 + dc);
        *(float4*)&zs[row * 68 + dc] = v;
    }
    __syncthreads();
    if (t < 64) {
        float z2 = 0.f;
#pragma unroll 8
        for (int d = 0; d < 64; ++d) { float zv = zs[t * 68 + d]; z2 = fmaf(zv, zv, z2); }
        z2s[t] = z2;
    }

    float best[4] = {INFINITY, INFINITY, INFINITY, INFINITY};
    int   bid[4]  = {0, 0, 0, 0};
    for (int t0 = 0; t0 < NE; t0 += 128) {
        __syncthreads();
#pragma unroll
        for (int s = 0; s < 8; ++s) {
            int c = t + (s << 8);
            int code = c >> 4, dc = (c & 15) << 2;
            float4 v = *(const float4*)(cb + (size_t)(t0 + code) * 64 + dc);
            cbs[(dc + 0) * 132 + code] = v.x; cbs[(dc + 1) * 132 + code] = v.y;
            cbs[(dc + 2) * 132 + code] = v.z; cbs[(dc + 3) * 132 + code] = v.w;
        }
        if (t < 128) c2s[t] = c2[t0 + t];
        __syncthreads();
        float acc[4][8] = {};
#pragma unroll 8
        for (int kk = 0; kk < 64; ++kk) {
            float a[4];
#pragma unroll
            for (int j = 0; j < 4; ++j) a[j] = zs[(4 * ty + j) * 68 + kk];
            float4 b0 = *(const float4*)&cbs[kk * 132 + (tx << 2)];
            float4 b1 = *(const float4*)&cbs[kk * 132 + 64 + (tx << 2)];
            float bv_[8] = {b0.x, b0.y, b0.z, b0.w, b1.x, b1.y, b1.z, b1.w};
#pragma unroll
            for (int r = 0; r < 4; ++r)
#pragma unroll
                for (int j = 0; j < 8; ++j)
                    acc[r][j] = fmaf(a[r], bv_[j], acc[r][j]);
        }
#pragma unroll
        for (int r = 0; r < 4; ++r) {
            float z2v = z2s[(ty << 2) + r];
#pragma unroll
            for (int j = 0; j < 8; ++j) {
                int cloc = (j < 4) ? ((tx << 2) + j) : (64 + (tx << 2) + (j - 4));
                float term = __fadd_rn(z2v, c2s[cloc]);
                float dist = __fsub_rn(term, __fmul_rn(2.0f, acc[r][j]));
                if (dist < best[r]) { best[r] = dist; bid[r] = t0 + cloc; }
            }
        }
    }
    __syncthreads();
    float* rbd = cbs;
    int*   rbi = (int*)(cbs + 1024);
#pragma unroll
    for (int r = 0; r < 4; ++r) {
        rbd[((ty << 2) + r) * 16 + tx] = best[r];
        rbi[((ty << 2) + r) * 16 + tx] = bid[r];
    }
    __syncthreads();
    if (t < 64) {
        float bd = INFINITY; int bi = 0;
#pragma unroll
        for (int q = 0; q < 16; ++q) {
            float d = rbd[t * 16 + q]; int i = rbi[t * 16 + q];
            if (d < bd || (d == bd && i < bi)) { bd = d; bi = i; }
        }
        bidxs[t] = bi;
        idx_dst[row0 + t] = (float)bi;
        atomicAdd(&counts[bi], 1);
    }
    __syncthreads();
    const int row = t >> 2, cq = t & 3;
    const int bi = bidxs[row];
    float lsum = 0.f;
#pragma unroll
    for (int dd = 0; dd < 16; dd += 4) {
        int d0 = (cq << 4) + dd;
        float4 q4 = *(const float4*)(cb + (size_t)bi * 64 + d0);
        float qv[4] = {q4.x, q4.y, q4.z, q4.w};
        float zst[4];
#pragma unroll
        for (int i = 0; i < 4; ++i) {
            float zv = zs[row * 68 + d0 + i];
            float df = qv[i] - zv;
            lsum = fmaf(df, df, lsum);
            zst[i] = __fadd_rn(zv, __fsub_rn(qv[i], zv));
            zb[(row0 + row) * 64 + d0 + i] = f2bf(zst[i]);
        }
        float2 o0 = {zst[0], zst[1]}, o1 = {zst[2], zst[3]};
        *(float2*)(zst_dst + (row0 + row) * 64 + d0) = o0;
        *(float2*)(zst_dst + (row0 + row) * 64 + d0 + 2) = o1;
    }
    lsum = wave_sum(lsum);
    if ((t & 63) == 0) red[t >> 6] = lsum;
    __syncthreads();
    if (t == 0) partials[blockIdx.x] = ((red[0] + red[1]) + red[2]) + red[3];
}

// -------------- finalize: loss + perplexity ---------------------------------------------
__global__ __launch_bounds__(256)
void fin_k(const float* __restrict__ partials, const int* __restrict__ counts,
           float* __restrict__ loss_out, float* __restrict__ perp_out)
{
    __shared__ float red[4];
    __shared__ float red2[4];
    const int tid = threadIdx.x;
    float v = 0.f;
    for (int c = tid; c < 1024; c += 256) v += partials[c];
    float s = wave_sum(v);
    if ((tid & 63) == 0) red[tid >> 6] = s;
    float ep = 0.f;
    for (int c = tid; c < NE; c += 256) {
        float e = (float)counts[c] * (1.0f / 65536.0f);
        ep += e * logf(e + 1e-10f);
    }
    ep = wave_sum(ep);
    if ((tid & 63) == 0) red2[tid >> 6] = ep;
    __syncthreads();
    if (tid == 0) {
        float S = ((red[0] + red[1]) + red[2]) + red[3];
        float E = ((red2[0] + red2[1]) + red2[2]) + red2[3];
        loss_out[0] = 1.25f * (S * (1.0f / 4194304.0f));
        perp_out[0] = expf(-E);
    }
}

extern "C" void kernel_launch(void* const* d_in, const int* in_sizes, int n_in,
                              void* d_out, int out_size, void* d_ws, size_t ws_size,
                              hipStream_t stream)
{
    const float* x       = (const float*)d_in[0];
    const float* a       = (const float*)d_in[1];
    const float* scale   = (const float*)d_in[2];
    const float* shift   = (const float*)d_in[3];
    const float* win_w   = (const float*)d_in[4];
    const float* win_b   = (const float*)d_in[5];
    const float* ain_w   = (const float*)d_in[6];
    const float* ain_b   = (const float*)d_in[7];
    const float* wres_w  = (const float*)d_in[8];
    const float* wres_b  = (const float*)d_in[9];
    const float* wres_g  = (const float*)d_in[10];
    const float* wres_be = (const float*)d_in[11];
    const float* ares_w  = (const float*)d_in[12];
    const float* ares_b  = (const float*)d_in[13];
    const float* ares_g  = (const float*)d_in[14];
    const float* ares_be = (const float*)d_in[15];
    const float* out_w   = (const float*)d_in[16];
    const float* out_b   = (const float*)d_in[17];
    const float* dec1_w  = (const float*)d_in[18];
    const float* dec1_b  = (const float*)d_in[19];
    const float* dres_w  = (const float*)d_in[20];
    const float* dres_b  = (const float*)d_in[21];
    const float* dres_g  = (const float*)d_in[22];
    const float* dres_be = (const float*)d_in[23];
    const float* dec2_w  = (const float*)d_in[24];
    const float* dec2_b  = (const float*)d_in[25];
    const float* cb      = (const float*)d_in[26];

    float* ws = (float*)d_ws;
    unsigned short* u = (unsigned short*)d_ws;
    // float-offset regions: avS [0,12.58M) | hS [12.58M,25.17M) | T [25.17M,33.55M) | wS | smalls
    unsigned short* avS0 = u;
    unsigned short* avS1 = u + 8388608;
    unsigned short* avS2 = u + 16777216;
    unsigned short* hS0  = u + 25165824;
    unsigned short* hS1  = u + 33554432;
    unsigned short* hS2  = u + 41943040;
    float* T  = ws + 25165824;
    float* ZE = T;
    // aliased (lifetime-checked):
    unsigned short* aS0 = u,               *aS1 = u + 2097152,  *aS2 = u + 4194304;
    unsigned short* xsS0 = u + 25165824,   *xsS1 = u + 27262976, *xsS2 = u + 29360128;
    unsigned short* ZB  = u;                         // 4194304 ushorts
    unsigned short* w1b = u + 4194304;               // 131072
    unsigned short* wrb = u + 4325376;               // 262144
    unsigned short* w2b = u + 4587520;               // 65536
    float* t_dec = ws + 4194304;                     // 8.39M floats, inside avS region
    float* hd    = ws + 12582912;                    // hS region (dead post z_e)
    unsigned short* Hb = (unsigned short*)(ws + 29360128);  // T upper half (dead post VQ)
    // weight splits
    unsigned short* wsb = u + 67108864;
    unsigned short* ainS0 = wsb,            *ainS1 = wsb + 65536,  *ainS2 = wsb + 131072;
    unsigned short* winS0 = wsb + 196608,   *winS1 = wsb + 262144, *winS2 = wsb + 327680;
    unsigned short* areS0 = wsb + 393216,   *areS1 = wsb + 655360, *areS2 = wsb + 917504;
    unsigned short* wreS0 = wsb + 1179648,  *wreS1 = wsb + 1441792,*wreS2 = wsb + 1703936;
    unsigned short* outS0 = wsb + 1966080,  *outS1 = wsb + 2097152,*outS2 = wsb + 2228224;
    float* c2v      = ws + 34800000;
    int*   counts   = (int*)(ws + 34801024);
    float* partials = ws + 34802048;

    float* dout = (float*)d_out;

    // --- splits ---
    prep_split_k<<<2048, 256, 0, stream>>>(x, scale, shift, xsS0, xsS1, xsS2);
    split3_k<<<2048, 256, 0, stream>>>(a, aS0, aS1, aS2, 524288);
    split3_k<<<64,  256, 0, stream>>>(ain_w, ainS0, ainS1, ainS2, 16384);
    split3_k<<<64,  256, 0, stream>>>(win_w, winS0, winS1, winS2, 16384);
    split3_k<<<256, 256, 0, stream>>>(ares_w, areS0, areS1, areS2, 65536);
    split3_k<<<256, 256, 0, stream>>>(wres_w, wreS0, wreS1, wreS2, 65536);
    split3_k<<<128, 256, 0, stream>>>(out_w, outS0, outS1, outS2, 32768);
    // --- encoder input projections ---
    gemm8_k<128><<<dim3(4, 128), 256, 0, stream>>>(aS0, aS1, aS2, ainS0, ainS1, ainS2, ain_b, T, DE);
    split3_k<<<8192, 256, 0, stream>>>(T, avS0, avS1, avS2, 2097152);
    gemm8_k<128><<<dim3(4, 128), 256, 0, stream>>>(xsS0, xsS1, xsS2, winS0, winS1, winS2, win_b, T, DE);
    split3_k<<<8192, 256, 0, stream>>>(T, hS0, hS1, hS2, 2097152);
    // --- encoder resblocks ---
    for (int r = 0; r < 3; ++r) {
        gemm8_k<512><<<dim3(4, 128), 256, 0, stream>>>(avS0, avS1, avS2, areS0, areS1, areS2, ares_b, T, DE);
        ln_av_k<<<4096, 256, 0, stream>>>(T, avS0, avS1, avS2, ares_g, ares_be);
        gemm8_k<512><<<dim3(4, 128), 256, 0, stream>>>(hS0, hS1, hS2, wreS0, wreS1, wreS2, wres_b, T, DE);
        ln_h_k<<<4096, 256, 0, stream>>>(T, hS0, hS1, hS2, avS0, avS1, avS2, wres_g, wres_be);
    }
    gemm8_k<512><<<dim3(2, 128), 256, 0, stream>>>(hS0, hS1, hS2, outS0, outS1, outS2, out_b, ZE, DOUTD);
    // --- VQ ---
    c2_k<<<NE / 256, 256, 0, stream>>>(cb, c2v);
    (void)hipMemsetAsync(counts, 0, NE * sizeof(int), stream);
    vq_k<<<1024, 256, 0, stream>>>(ZE, cb, c2v, dout + O_IDX, dout + O_ZQ, ZB, counts, partials);
    fin_k<<<1, 256, 0, stream>>>(partials, counts, dout, dout + O_PERP);
    // --- decoder (bf16 MFMA) ---
    cvt_k<<<512,  256, 0, stream>>>(dec1_w, w1b, DE * DOUTD);
    cvt_k<<<1024, 256, 0, stream>>>(dres_w, wrb, DE * DE);
    cvt_k<<<256,  256, 0, stream>>>(dec2_w, w2b, IND * DE);
    gemmbf_k<256, 1><<<dim3(DE / 128, BROWS / 128), 256, 0, stream>>>(
        (const short*)ZB, (const short*)w1b, dec1_b, hd, DE, Hb, nullptr, nullptr);
    for (int r = 0; r < 3; ++r) {
        gemmbf_k<512, 0><<<dim3(DE / 128, BROWS / 128), 256, 0, stream>>>(
            (const short*)Hb, (const short*)wrb, dres_b, t_dec, DE, nullptr, nullptr, nullptr);
        ln_dec_k<<<4096, 256, 0, stream>>>(t_dec, hd, dres_g, dres_be, Hb);
    }
    gemmbf_k<512, 2><<<dim3(IND / 128, BROWS / 128), 256, 0, stream>>>(
        (const short*)Hb, (const short*)w2b, dec2_b, dout + O_XHAT, IND, nullptr, scale, shift);
}